// Round 8
// baseline (274.655 us; speedup 1.0000x reference)
//
#include <hip/hip_runtime.h>
#include <cstdint>

#define NPROP  48
#define MGRID  216
#define NPT    (NPROP*MGRID)      // 10368 points per batch
#define KPT    2048
#define CFEAT  128
#define R0SQ   0.64f              // 0.8^2
#define R1SQ   2.56f              // 1.6^2
#define NS0    16
#define NS1    32
#define KRED   (CFEAT*MGRID)      // 27648
#define NPOINTS (2*NPT)           // 20736
#define NKSPLIT 108               // K per split = 256

typedef float f32x4  __attribute__((ext_vector_type(4)));
typedef short bf16x8 __attribute__((ext_vector_type(8)));
typedef unsigned long long ull;

// workspace layout (floats) — total 8,511,488 fl = 34.0 MB
#define AFRAG_OFF 0                           // W-frags hi+lo: 8192 floats (32 KB)
#define KX4_OFF   8192                        // kxyz4 [2][2048] f32x4 = 16384
#define Q0_OFF    24576                       // Q [2 s][2 b][2048 k][64 o] = 524288
#define POOL_OFF  548864                      // poolT [20736 p][128 c] = 2654208
#define PT_OFF    3203072                     // pool2 [96 r][27648 (c*216+g)] = 2654208
#define PART_OFF  5857280                     // part [108 ks][96 r][256 o] = 2654208

__device__ __forceinline__ unsigned short bf_rne(float x) {
    unsigned u = __float_as_uint(x);
    return (unsigned short)((u + 0x7fffu + ((u >> 16) & 1u)) >> 16);
}
__device__ __forceinline__ float bf_f32(unsigned short h) {
    return __uint_as_float(((unsigned)h) << 16);
}

// ---------------------------------------------------------------------------
// K0: blocks 0-15: layer-2 weight fragments (hi/lo bf16 split).
// Fragment layout (symmetric for A/B operands of 16x16x32):
//   lane l holds X[idx = l&15][k = (l>>4)*8 + j], j=0..7.
// Used as the *B* operand now (idx = channel n); packing is unchanged.
//     blocks 16-79: pack kxyz4 = (x,y,z,kn2) for the ball query.
// ---------------------------------------------------------------------------
__global__ __launch_bounds__(64) void k_pre(
    const float* __restrict__ kxyz,
    const float* __restrict__ w01, const float* __restrict__ w11,
    float* __restrict__ ws)
{
    int bid = blockIdx.x;
    if (bid < 16) {
        int kc = bid & 1, ot = (bid >> 1) & 3, s = bid >> 3;
        const float* W = s ? w11 : w01;
        int l   = threadIdx.x;
        int row = ot*16 + (l & 15);
        int k0  = kc*32 + (l >> 4)*8;
        union { unsigned short u16[8]; bf16x8 v; } hh, hl;
#pragma unroll
        for (int j = 0; j < 8; ++j) {
            float x  = W[row*64 + k0 + j];
            unsigned short hi = bf_rne(x);
            hh.u16[j] = hi;
            hl.u16[j] = bf_rne(x - bf_f32(hi));
        }
        bf16x8* Whi = (bf16x8*)(ws + AFRAG_OFF);
        bf16x8* Wlo = Whi + 16*64;
        int fi = (s*4 + ot)*2 + kc;
        Whi[fi*64 + l] = hh.v;
        Wlo[fi*64 + l] = hl.v;
    } else {
        int idx = (bid - 16)*64 + threadIdx.x;      // = b*KPT + k, < 4096
        const float* kp = kxyz + (size_t)idx*3;
        float kx = kp[0], ky = kp[1], kz = kp[2];
        float kn2 = fmaf(kz, kz, fmaf(ky, ky, kx*kx));
        f32x4 v = {kx, ky, kz, kn2};
        ((f32x4*)(ws + KX4_OFF))[idx] = v;
    }
}

// ---------------------------------------------------------------------------
// K2: Q[s][b][k][o] = b0_s[o] + W_s[o][0:3].kxyz + W_s[o][3:].feats
// ---------------------------------------------------------------------------
__global__ __launch_bounds__(256) void k_qproj(
    const float* __restrict__ kxyz, const float* __restrict__ feats,
    const float* __restrict__ w0, const float* __restrict__ b0,
    const float* __restrict__ w1, const float* __restrict__ b1,
    float* __restrict__ ws)
{
    __shared__ float wl[64*131];
    int bid  = blockIdx.x;
    int kgrp = bid & 511;
    int s    = (bid >> 9) & 1;
    int b    = bid >> 10;
    const float* W    = s ? w1 : w0;
    const float* bias = s ? b1 : b0;
    for (int i = threadIdx.x; i < 64*131; i += 256) wl[i] = W[i];
    __syncthreads();
    int k = kgrp*4 + (threadIdx.x >> 6);
    int o = threadIdx.x & 63;
    float acc = bias[o];
    const float* kp = kxyz + ((size_t)b*KPT + k)*3;
    acc = fmaf(wl[o*131+0], kp[0], acc);
    acc = fmaf(wl[o*131+1], kp[1], acc);
    acc = fmaf(wl[o*131+2], kp[2], acc);
    const float* f = feats + (size_t)b*CFEAT*KPT + k;
#pragma unroll 8
    for (int c = 0; c < CFEAT; ++c)
        acc = fmaf(wl[o*131+3+c], f[(size_t)c*KPT], acc);
    ws[Q0_OFF + (size_t)s*(2*KPT*64) + ((size_t)b*KPT + k)*64 + o] = acc;
}

// ---------------------------------------------------------------------------
// K3 main: one WAVE per point. Swapped-operand MFMA: D = H(samples) x W2^T,
// so the sample-max pool is reg-max + 2 shfl_xor (no LDS stage round-trip).
// ---------------------------------------------------------------------------
template <int NST>
__device__ __forceinline__ void build_hfrag(
    const float* __restrict__ Qb, const int* __restrict__ idxl,
    const float* __restrict__ u_lds,
    bf16x8 (&Hhi)[NST][2], bf16x8 (&Hlo)[NST][2], int lane)
{
    const int g = lane >> 4;
#pragma unroll
    for (int st = 0; st < NST; ++st) {
        int sp = idxl[st*16 + (lane & 15)];
        const float* qr = Qb + ((size_t)sp << 6) + g*8;
#pragma unroll
        for (int kc = 0; kc < 2; ++kc) {
            f32x4 q0 = *(const f32x4*)(qr + kc*32);
            f32x4 q1 = *(const f32x4*)(qr + kc*32 + 4);
            f32x4 u0 = *(const f32x4*)(u_lds + kc*32 + g*8);
            f32x4 u1 = *(const f32x4*)(u_lds + kc*32 + g*8 + 4);
            union { unsigned short u16[8]; bf16x8 v; } hh, hl;
#pragma unroll
            for (int j = 0; j < 4; ++j) {
                float x = fmaxf(q0[j] - u0[j], 0.f);
                unsigned short hi = bf_rne(x);
                hh.u16[j] = hi;
                hl.u16[j] = bf_rne(x - bf_f32(hi));
                float y = fmaxf(q1[j] - u1[j], 0.f);
                unsigned short hi2 = bf_rne(y);
                hh.u16[j+4] = hi2;
                hl.u16[j+4] = bf_rne(y - bf_f32(hi2));
            }
            Hhi[st][kc] = hh.v;
            Hlo[st][kc] = hl.v;
        }
    }
}

template <int NST>
__device__ __forceinline__ float eval_T(
    const bf16x8* Whi, const bf16x8* Wlo,      // LDS W-fragments
    const float* __restrict__ bs,
    const bf16x8 (&Hhi)[NST][2], const bf16x8 (&Hlo)[NST][2],
    int sbase, int lane)
{
    float r0, r1, r2, r3;
#define EVAL_OT(OT, ROUT)                                                     \
    {                                                                         \
        int fi = (sbase + (OT))*2;                                            \
        bf16x8 wh0 = Whi[(fi+0)*64 + lane];                                   \
        bf16x8 wh1 = Whi[(fi+1)*64 + lane];                                   \
        bf16x8 wl0 = Wlo[(fi+0)*64 + lane];                                   \
        bf16x8 wl1 = Wlo[(fi+1)*64 + lane];                                   \
        float bc = bs[(OT)*16 + (lane & 15)];                                 \
        f32x4 rmax = {0.f, 0.f, 0.f, 0.f};                                    \
        _Pragma("unroll")                                                     \
        for (int st = 0; st < NST; ++st) {                                    \
            f32x4 acc = {0.f, 0.f, 0.f, 0.f};                                 \
            acc = __builtin_amdgcn_mfma_f32_16x16x32_bf16(Hlo[st][0], wh0, acc, 0,0,0); \
            acc = __builtin_amdgcn_mfma_f32_16x16x32_bf16(Hlo[st][1], wh1, acc, 0,0,0); \
            acc = __builtin_amdgcn_mfma_f32_16x16x32_bf16(Hhi[st][0], wl0, acc, 0,0,0); \
            acc = __builtin_amdgcn_mfma_f32_16x16x32_bf16(Hhi[st][1], wl1, acc, 0,0,0); \
            acc = __builtin_amdgcn_mfma_f32_16x16x32_bf16(Hhi[st][0], wh0, acc, 0,0,0); \
            acc = __builtin_amdgcn_mfma_f32_16x16x32_bf16(Hhi[st][1], wh1, acc, 0,0,0); \
            _Pragma("unroll")                                                 \
            for (int r = 0; r < 4; ++r)                                       \
                rmax[r] = fmaxf(rmax[r], fmaxf(acc[r] + bc, 0.f));            \
        }                                                                     \
        float mm = fmaxf(fmaxf(rmax[0], rmax[1]), fmaxf(rmax[2], rmax[3]));   \
        mm = fmaxf(mm, __shfl_xor(mm, 16));                                   \
        mm = fmaxf(mm, __shfl_xor(mm, 32));                                   \
        ROUT = mm;                                                            \
    }
    EVAL_OT(0, r0) EVAL_OT(1, r1) EVAL_OT(2, r2) EVAL_OT(3, r3)
#undef EVAL_OT
    // lane's channel = lane (0..63): pick tile ot = lane>>4 via cndmask chain
    float v01 = (lane & 16) ? r1 : r0;
    float v23 = (lane & 16) ? r3 : r2;
    return (lane & 32) ? v23 : v01;
}

__global__ __launch_bounds__(512, 6) void k_main(
    const float* __restrict__ proposals, const float* __restrict__ grid_noise,
    const float* __restrict__ w00, const float* __restrict__ b01,
    const float* __restrict__ w10, const float* __restrict__ b11,
    float* __restrict__ ws)
{
    __shared__ __align__(16) float afrag[8192];      // 32 KB: Whi | Wlo
    __shared__ int idx0s[8][NS0];
    __shared__ int idx1s[8][NS1];
    __shared__ __align__(16) float u0l[8][64], u1l[8][64];
    const int wid  = threadIdx.x >> 6;
    const int lane = threadIdx.x & 63;

    // ---- cooperative stage of all W-fragments into LDS (once per block)
    {
        const f32x4* src = (const f32x4*)(ws + AFRAG_OFF);
        f32x4* dst = (f32x4*)afrag;
        for (int t = threadIdx.x; t < 2048; t += 512) dst[t] = src[t];
    }
    __syncthreads();

    const int p = blockIdx.x*8 + wid;            // < 20736
    int b   = p / NPT;
    int rem = p - b*NPT;
    int i   = rem / MGRID;
    int g   = rem - i*MGRID;

    float a0x = w00[lane*131+0], a0y = w00[lane*131+1], a0z = w00[lane*131+2];
    float a1x = w10[lane*131+0], a1y = w10[lane*131+1], a1z = w10[lane*131+2];

    const float* pr = proposals  + ((size_t)b*NPROP + i)*7;
    const float* gn = grid_noise + (((size_t)b*NPROP + i)*MGRID + g)*3;
    float gx = gn[0]*pr[3], gy = gn[1]*pr[4], gz = gn[2]*pr[5];
    float th = pr[6];
    float ss = sinf(th), cc = cosf(th);
    float nx = cc*gx - ss*gy + pr[0];
    float ny = ss*gx + cc*gy + pr[1];
    float nz = gz + pr[2];
    float pn2 = nx*nx + ny*ny + nz*nz;
    u0l[wid][lane] = a0x*nx + a0y*ny + a0z*nz;
    u1l[wid][lane] = a1x*nx + a1y*ny + a1z*nz;

    // ---- dual-radius ball query: one scan, per-radius guarded processing
    int* idx0 = idx0s[wid];
    int* idx1 = idx1s[wid];
    int cnt0 = 0, cnt1 = 0;
    const f32x4* kx4 = (const f32x4*)(ws + KX4_OFF) + (size_t)b*KPT;
    ull ltm = (1ull << lane) - 1ull;

#define BQ_PROC(D2, RSQ, KK, CNT, IDX, NSV)                                   \
    {                                                                         \
        ull m = __ballot((D2) < RSQ);                                         \
        if (m) {                                                              \
            int pre = __popcll(m & ltm);                                      \
            if (((m >> lane) & 1ull) && CNT + pre < NSV) IDX[CNT + pre] = (KK);\
            CNT += __popcll(m);                                               \
        }                                                                     \
    }

    for (int ck = 0; ck < KPT/64; ck += 2) {
        f32x4 ka  = kx4[ck*64 + lane];
        f32x4 kc2 = kx4[ck*64 + 64 + lane];
        float dta = fmaf(nz, ka.z, fmaf(ny, ka.y, nx*ka.x));
        float d2a = fmaf(-2.f, dta, pn2 + ka.w);
        float dtb = fmaf(nz, kc2.z, fmaf(ny, kc2.y, nx*kc2.x));
        float d2b = fmaf(-2.f, dtb, pn2 + kc2.w);
        int kka = ck*64 + lane, kkb = kka + 64;
        if (cnt0 < NS0) {                        // wave-uniform guard
            BQ_PROC(d2a, R0SQ, kka, cnt0, idx0, NS0)
            BQ_PROC(d2b, R0SQ, kkb, cnt0, idx0, NS0)
        }
        if (cnt1 < NS1) {                        // wave-uniform guard
            BQ_PROC(d2a, R1SQ, kka, cnt1, idx1, NS1)
            BQ_PROC(d2b, R1SQ, kkb, cnt1, idx1, NS1)
        }
        if (cnt0 >= NS0 && cnt1 >= NS1) break;   // wave-uniform
    }
#undef BQ_PROC

    if (lane == 0) {
        if (cnt0 == 0) idx0[0] = 0;              // empty-ball fallback
        if (cnt1 == 0) idx1[0] = 0;
    }
    asm volatile("s_waitcnt lgkmcnt(0)" ::: "memory");
    __builtin_amdgcn_wave_barrier();
    int na0 = cnt0 ? min(cnt0, NS0) : 1;
    int na1 = cnt1 ? min(cnt1, NS1) : 1;
    int f0 = idx0[0], f1 = idx1[0];
    if (lane >= na0 && lane < NS0) idx0[lane] = f0;   // pad like reference
    if (lane >= na1 && lane < NS1) idx1[lane] = f1;
    asm volatile("s_waitcnt lgkmcnt(0)" ::: "memory");
    __builtin_amdgcn_wave_barrier();

    // ---- gather+convert H-fragments for BOTH scales, then MFMA ----
    const float*  Qb0 = ws + Q0_OFF + (size_t)b*(KPT*64);
    const float*  Qb1 = ws + Q0_OFF + (size_t)(2*KPT*64) + (size_t)b*(KPT*64);
    const bf16x8* Whi = (const bf16x8*)afrag;         // LDS
    const bf16x8* Wlo = Whi + 16*64;

    bf16x8 H0hi[1][2], H0lo[1][2], H1hi[2][2], H1lo[2][2];
    build_hfrag<1>(Qb0, idx0, u0l[wid], H0hi, H0lo, lane);
    build_hfrag<2>(Qb1, idx1, u1l[wid], H1hi, H1lo, lane);

    float mx0 = eval_T<1>(Whi, Wlo, b01, H0hi, H0lo, 0, lane);
    float mx1 = eval_T<2>(Whi, Wlo, b11, H1hi, H1lo, 4, lane);

    // coalesced pooled store: poolT[p][c]
    ws[POOL_OFF + (size_t)p*CFEAT + lane]      = mx0;
    ws[POOL_OFF + (size_t)p*CFEAT + 64 + lane] = mx1;
}

// ---------------------------------------------------------------------------
// K_ptr: pool2[r][c*216+g] = poolT[(r*216+g)][c]  (per-row transpose, 21 MB)
// ---------------------------------------------------------------------------
template <int W>
__device__ __forceinline__ void ptr_tile(const float* __restrict__ in,
                                         float* __restrict__ out,
                                         float* __restrict__ t, int g0)
{
    for (int idx = threadIdx.x; idx < 128*W; idx += 256) {
        int gg = idx >> 7, c = idx & 127;
        t[c*(W+1) + gg] = in[(size_t)(g0+gg)*128 + c];   // coalesced along c
    }
    __syncthreads();
    for (int idx = threadIdx.x; idx < 128*W; idx += 256) {
        int c = idx / W, gg = idx - c*W;
        out[c*216 + g0 + gg] = t[c*(W+1) + gg];          // coalesced along g
    }
}

__global__ __launch_bounds__(256) void k_ptr(float* __restrict__ ws)
{
    __shared__ float t[128*33];
    int bid = blockIdx.x;
    int row = bid / 7, tt = bid - row*7;
    const float* in = ws + POOL_OFF + (size_t)row*MGRID*CFEAT;
    float* out = ws + PT_OFF + (size_t)row*KRED;
    if (tt < 6) ptr_tile<32>(in, out, t, tt*32);
    else        ptr_tile<24>(in, out, t, 192);
}

// ---------------------------------------------------------------------------
// K4: part[ks][96][256] = A[96][ksK] * B[256][ksK]^T  (no atomics)
// grid = 108 ksplits x 4 o-tiles of 64; K per split = 256 (4 chunks of 64)
// ---------------------------------------------------------------------------
__global__ __launch_bounds__(256) void k_red0(
    const float* __restrict__ A, const float* __restrict__ w0,
    float* __restrict__ part)
{
    __shared__ __align__(16) float Al[96*68];
    __shared__ __align__(16) float Bl[64*68];
    int bid = blockIdx.x;
    int ot  = bid & 3;
    int ks  = bid >> 2;                      // 0..107
    int tid = threadIdx.x;
    int tx  = tid & 15, ty = tid >> 4;
    float acc[6][4] = {};

    for (int chunk = 0; chunk < 4; ++chunk) {
        int kk0 = ks*256 + chunk*64;
#pragma unroll
        for (int j = 0; j < 6; ++j) {        // stage A 96x64
            int f4i = tid + j*256;
            int rr = f4i >> 4, c4 = f4i & 15;
            float4 v = *(const float4*)(A + (size_t)rr*KRED + kk0 + c4*4);
            *(float4*)(Al + rr*68 + c4*4) = v;
        }
#pragma unroll
        for (int j = 0; j < 4; ++j) {        // stage B 64x64
            int f4i = tid + j*256;
            int rr = f4i >> 4, c4 = f4i & 15;
            float4 v = *(const float4*)(w0 + (size_t)(ot*64+rr)*KRED + kk0 + c4*4);
            *(float4*)(Bl + rr*68 + c4*4) = v;
        }
        __syncthreads();
#pragma unroll
        for (int k4 = 0; k4 < 16; ++k4) {
            float4 av[6], bv[4];
#pragma unroll
            for (int q = 0; q < 6; ++q) av[q] = *(const float4*)(Al + (ty*6+q)*68 + k4*4);
#pragma unroll
            for (int u = 0; u < 4; ++u) bv[u] = *(const float4*)(Bl + (u*16+tx)*68 + k4*4);
#pragma unroll
            for (int q = 0; q < 6; ++q)
#pragma unroll
                for (int u = 0; u < 4; ++u) {
                    acc[q][u] = fmaf(av[q].x, bv[u].x, acc[q][u]);
                    acc[q][u] = fmaf(av[q].y, bv[u].y, acc[q][u]);
                    acc[q][u] = fmaf(av[q].z, bv[u].z, acc[q][u]);
                    acc[q][u] = fmaf(av[q].w, bv[u].w, acc[q][u]);
                }
        }
        __syncthreads();
    }
    float* pp = part + (size_t)ks*(96*256);
#pragma unroll
    for (int q = 0; q < 6; ++q)
#pragma unroll
        for (int u = 0; u < 4; ++u)
            pp[(size_t)(ty*6+q)*256 + ot*64 + u*16 + tx] = acc[q][u];
}

// ---------------------------------------------------------------------------
// K5: out = relu(relu(sum_ks part + b0) @ W1^T + b1)
// ---------------------------------------------------------------------------
__global__ __launch_bounds__(256) void k_fin(
    const float* __restrict__ part, const float* __restrict__ rb0,
    const float* __restrict__ w1, const float* __restrict__ rb1,
    float* __restrict__ out)
{
    __shared__ __align__(16) float hbuf[256];
    int r = blockIdx.x, o = threadIdx.x;
    const float* pp = part + (size_t)r*256 + o;
    float s0 = 0.f, s1 = 0.f, s2 = 0.f, s3 = 0.f;
#pragma unroll 4
    for (int ks = 0; ks < NKSPLIT; ks += 4) {
        s0 += pp[(size_t)(ks+0)*(96*256)];
        s1 += pp[(size_t)(ks+1)*(96*256)];
        s2 += pp[(size_t)(ks+2)*(96*256)];
        s3 += pp[(size_t)(ks+3)*(96*256)];
    }
    float h = fmaxf(((s0 + s1) + (s2 + s3)) + rb0[o], 0.f);
    hbuf[o] = h;
    __syncthreads();
    float a0 = rb1[o], a1 = 0.f, a2 = 0.f, a3 = 0.f;
    const float4* wrow = (const float4*)(w1 + (size_t)o*256);
    const float4* hv   = (const float4*)hbuf;
#pragma unroll 8
    for (int j = 0; j < 64; ++j) {
        float4 w = wrow[j], x = hv[j];
        a0 = fmaf(w.x, x.x, a0);
        a1 = fmaf(w.y, x.y, a1);
        a2 = fmaf(w.z, x.z, a2);
        a3 = fmaf(w.w, x.w, a3);
    }
    out[(size_t)r*256 + o] = fmaxf((a0 + a1) + (a2 + a3), 0.f);
}

// ---------------------------------------------------------------------------
extern "C" void kernel_launch(void* const* d_in, const int* in_sizes, int n_in,
                              void* d_out, int out_size, void* d_ws, size_t ws_size,
                              hipStream_t stream)
{
    (void)in_sizes; (void)n_in; (void)out_size; (void)ws_size;
    const float* proposals = (const float*)d_in[0];
    const float* kxyz      = (const float*)d_in[1];
    const float* feats     = (const float*)d_in[2];
    const float* gnoise    = (const float*)d_in[3];
    const float* w0_0 = (const float*)d_in[4];
    const float* b0_0 = (const float*)d_in[5];
    const float* w0_1 = (const float*)d_in[6];
    const float* b0_1 = (const float*)d_in[7];
    const float* w1_0 = (const float*)d_in[8];
    const float* b1_0 = (const float*)d_in[9];
    const float* w1_1 = (const float*)d_in[10];
    const float* b1_1 = (const float*)d_in[11];
    const float* rw0  = (const float*)d_in[12];
    const float* rb0  = (const float*)d_in[13];
    const float* rw1  = (const float*)d_in[14];
    const float* rb1  = (const float*)d_in[15];
    float* ws  = (float*)d_ws;
    float* out = (float*)d_out;

    k_pre  <<<  80,  64, 0, stream>>>(kxyz, w0_1, w1_1, ws);
    k_qproj<<<2048, 256, 0, stream>>>(kxyz, feats, w0_0, b0_0, w1_0, b1_0, ws);
    k_main <<<2592, 512, 0, stream>>>(proposals, gnoise,
                                      w0_0, b0_1, w1_0, b1_1, ws);
    k_ptr  <<< 672, 256, 0, stream>>>(ws);
    k_red0 <<< 432, 256, 0, stream>>>(ws + PT_OFF, rw0, ws + PART_OFF);
    k_fin  <<<  96, 256, 0, stream>>>(ws + PART_OFF, rb0, rw1, rb1, out);
}

// Round 9
// 231.110 us; speedup vs baseline: 1.1884x; 1.1884x over previous
//
#include <hip/hip_runtime.h>
#include <cstdint>

#define NPROP  48
#define MGRID  216
#define NPT    (NPROP*MGRID)      // 10368 points per batch
#define KPT    2048
#define CFEAT  128
#define R0SQ   0.64f              // 0.8^2
#define R1SQ   2.56f              // 1.6^2
#define NS0    16
#define NS1    32
#define KRED   (CFEAT*MGRID)      // 27648
#define NPOINTS (2*NPT)           // 20736
#define NKSPLIT 108               // K per split = 256

typedef float f32x4  __attribute__((ext_vector_type(4)));
typedef short bf16x8 __attribute__((ext_vector_type(8)));
typedef unsigned long long ull;

// workspace layout (floats) — total 8,511,488 fl = 34.0 MB
#define AFRAG_OFF 0                           // W-frags hi+lo: 8192 floats (32 KB)
#define KX4_OFF   8192                        // kxyz4 [2][2048] f32x4 = 16384
#define Q0_OFF    24576                       // Q [2 s][2 b][2048 k][64 o] = 524288
#define POOL_OFF  548864                      // poolT [20736 p][128 c] = 2654208
#define PT_OFF    3203072                     // pool2 [96 r][27648 (c*216+g)] = 2654208
#define PART_OFF  5857280                     // part [108 ks][96 r][256 o] = 2654208

__device__ __forceinline__ unsigned short bf_rne(float x) {
    unsigned u = __float_as_uint(x);
    return (unsigned short)((u + 0x7fffu + ((u >> 16) & 1u)) >> 16);
}
__device__ __forceinline__ float bf_f32(unsigned short h) {
    return __uint_as_float(((unsigned)h) << 16);
}

// ---------------------------------------------------------------------------
// K0: blocks 0-15: layer-2 weight fragments (hi/lo bf16 split).
// Fragment layout (symmetric for A/B operands of 16x16x32):
//   lane l holds X[idx = l&15][k = (l>>4)*8 + j], j=0..7.
// Used as the *B* operand (idx = channel n).
//     blocks 16-79: pack kxyz4 = (x,y,z,kn2) for the ball query.
// ---------------------------------------------------------------------------
__global__ __launch_bounds__(64) void k_pre(
    const float* __restrict__ kxyz,
    const float* __restrict__ w01, const float* __restrict__ w11,
    float* __restrict__ ws)
{
    int bid = blockIdx.x;
    if (bid < 16) {
        int kc = bid & 1, ot = (bid >> 1) & 3, s = bid >> 3;
        const float* W = s ? w11 : w01;
        int l   = threadIdx.x;
        int row = ot*16 + (l & 15);
        int k0  = kc*32 + (l >> 4)*8;
        union { unsigned short u16[8]; bf16x8 v; } hh, hl;
#pragma unroll
        for (int j = 0; j < 8; ++j) {
            float x  = W[row*64 + k0 + j];
            unsigned short hi = bf_rne(x);
            hh.u16[j] = hi;
            hl.u16[j] = bf_rne(x - bf_f32(hi));
        }
        bf16x8* Whi = (bf16x8*)(ws + AFRAG_OFF);
        bf16x8* Wlo = Whi + 16*64;
        int fi = (s*4 + ot)*2 + kc;
        Whi[fi*64 + l] = hh.v;
        Wlo[fi*64 + l] = hl.v;
    } else {
        int idx = (bid - 16)*64 + threadIdx.x;      // = b*KPT + k, < 4096
        const float* kp = kxyz + (size_t)idx*3;
        float kx = kp[0], ky = kp[1], kz = kp[2];
        float kn2 = fmaf(kz, kz, fmaf(ky, ky, kx*kx));
        f32x4 v = {kx, ky, kz, kn2};
        ((f32x4*)(ws + KX4_OFF))[idx] = v;
    }
}

// ---------------------------------------------------------------------------
// K2: Q[s][b][k][o] = b0_s[o] + W_s[o][0:3].kxyz + W_s[o][3:].feats
// ---------------------------------------------------------------------------
__global__ __launch_bounds__(256) void k_qproj(
    const float* __restrict__ kxyz, const float* __restrict__ feats,
    const float* __restrict__ w0, const float* __restrict__ b0,
    const float* __restrict__ w1, const float* __restrict__ b1,
    float* __restrict__ ws)
{
    __shared__ float wl[64*131];
    int bid  = blockIdx.x;
    int kgrp = bid & 511;
    int s    = (bid >> 9) & 1;
    int b    = bid >> 10;
    const float* W    = s ? w1 : w0;
    const float* bias = s ? b1 : b0;
    for (int i = threadIdx.x; i < 64*131; i += 256) wl[i] = W[i];
    __syncthreads();
    int k = kgrp*4 + (threadIdx.x >> 6);
    int o = threadIdx.x & 63;
    float acc = bias[o];
    const float* kp = kxyz + ((size_t)b*KPT + k)*3;
    acc = fmaf(wl[o*131+0], kp[0], acc);
    acc = fmaf(wl[o*131+1], kp[1], acc);
    acc = fmaf(wl[o*131+2], kp[2], acc);
    const float* f = feats + (size_t)b*CFEAT*KPT + k;
#pragma unroll 8
    for (int c = 0; c < CFEAT; ++c)
        acc = fmaf(wl[o*131+3+c], f[(size_t)c*KPT], acc);
    ws[Q0_OFF + (size_t)s*(2*KPT*64) + ((size_t)b*KPT + k)*64 + o] = acc;
}

// ---------------------------------------------------------------------------
// K3 main: one WAVE per point. Swapped-operand MFMA: D = H(samples) x W2^T,
// so the sample-max pool is reg-max + 2 shfl_xor (no LDS stage round-trip).
// ---------------------------------------------------------------------------
template <int NST>
__device__ __forceinline__ void build_hfrag(
    const float* __restrict__ Qb, const int* __restrict__ idxl,
    const float* __restrict__ u_lds,
    bf16x8 (&Hhi)[NST][2], bf16x8 (&Hlo)[NST][2], int lane)
{
    const int g = lane >> 4;
#pragma unroll
    for (int st = 0; st < NST; ++st) {
        int sp = idxl[st*16 + (lane & 15)];
        const float* qr = Qb + ((size_t)sp << 6) + g*8;
#pragma unroll
        for (int kc = 0; kc < 2; ++kc) {
            f32x4 q0 = *(const f32x4*)(qr + kc*32);
            f32x4 q1 = *(const f32x4*)(qr + kc*32 + 4);
            f32x4 u0 = *(const f32x4*)(u_lds + kc*32 + g*8);
            f32x4 u1 = *(const f32x4*)(u_lds + kc*32 + g*8 + 4);
            union { unsigned short u16[8]; bf16x8 v; } hh, hl;
#pragma unroll
            for (int j = 0; j < 4; ++j) {
                float x = fmaxf(q0[j] - u0[j], 0.f);
                unsigned short hi = bf_rne(x);
                hh.u16[j] = hi;
                hl.u16[j] = bf_rne(x - bf_f32(hi));
                float y = fmaxf(q1[j] - u1[j], 0.f);
                unsigned short hi2 = bf_rne(y);
                hh.u16[j+4] = hi2;
                hl.u16[j+4] = bf_rne(y - bf_f32(hi2));
            }
            Hhi[st][kc] = hh.v;
            Hlo[st][kc] = hl.v;
        }
    }
}

template <int NST>
__device__ __forceinline__ float eval_T(
    const bf16x8* Whi, const bf16x8* Wlo,      // LDS W-fragments
    const float* __restrict__ bs,
    const bf16x8 (&Hhi)[NST][2], const bf16x8 (&Hlo)[NST][2],
    int sbase, int lane)
{
    float r0, r1, r2, r3;
#define EVAL_OT(OT, ROUT)                                                     \
    {                                                                         \
        int fi = (sbase + (OT))*2;                                            \
        bf16x8 wh0 = Whi[(fi+0)*64 + lane];                                   \
        bf16x8 wh1 = Whi[(fi+1)*64 + lane];                                   \
        bf16x8 wl0 = Wlo[(fi+0)*64 + lane];                                   \
        bf16x8 wl1 = Wlo[(fi+1)*64 + lane];                                   \
        float bc = bs[(OT)*16 + (lane & 15)];                                 \
        f32x4 rmax = {0.f, 0.f, 0.f, 0.f};                                    \
        _Pragma("unroll")                                                     \
        for (int st = 0; st < NST; ++st) {                                    \
            f32x4 acc = {0.f, 0.f, 0.f, 0.f};                                 \
            acc = __builtin_amdgcn_mfma_f32_16x16x32_bf16(Hlo[st][0], wh0, acc, 0,0,0); \
            acc = __builtin_amdgcn_mfma_f32_16x16x32_bf16(Hlo[st][1], wh1, acc, 0,0,0); \
            acc = __builtin_amdgcn_mfma_f32_16x16x32_bf16(Hhi[st][0], wl0, acc, 0,0,0); \
            acc = __builtin_amdgcn_mfma_f32_16x16x32_bf16(Hhi[st][1], wl1, acc, 0,0,0); \
            acc = __builtin_amdgcn_mfma_f32_16x16x32_bf16(Hhi[st][0], wh0, acc, 0,0,0); \
            acc = __builtin_amdgcn_mfma_f32_16x16x32_bf16(Hhi[st][1], wh1, acc, 0,0,0); \
            _Pragma("unroll")                                                 \
            for (int r = 0; r < 4; ++r)                                       \
                rmax[r] = fmaxf(rmax[r], fmaxf(acc[r] + bc, 0.f));            \
        }                                                                     \
        float mm = fmaxf(fmaxf(rmax[0], rmax[1]), fmaxf(rmax[2], rmax[3]));   \
        mm = fmaxf(mm, __shfl_xor(mm, 16));                                   \
        mm = fmaxf(mm, __shfl_xor(mm, 32));                                   \
        ROUT = mm;                                                            \
    }
    EVAL_OT(0, r0) EVAL_OT(1, r1) EVAL_OT(2, r2) EVAL_OT(3, r3)
#undef EVAL_OT
    // lane's channel = lane (0..63): pick tile ot = lane>>4 via cndmask chain
    float v01 = (lane & 16) ? r1 : r0;
    float v23 = (lane & 16) ? r3 : r2;
    return (lane & 32) ? v23 : v01;
}

__global__ __launch_bounds__(512, 4) void k_main(   // cap 128 VGPR: no spill
    const float* __restrict__ proposals, const float* __restrict__ grid_noise,
    const float* __restrict__ w00, const float* __restrict__ b01,
    const float* __restrict__ w10, const float* __restrict__ b11,
    float* __restrict__ ws)
{
    __shared__ __align__(16) float afrag[8192];      // 32 KB: Whi | Wlo
    __shared__ int idx0s[8][NS0];
    __shared__ int idx1s[8][NS1];
    __shared__ __align__(16) float u0l[8][64], u1l[8][64];
    const int wid  = threadIdx.x >> 6;
    const int lane = threadIdx.x & 63;

    // ---- cooperative stage of all W-fragments into LDS (once per block)
    {
        const f32x4* src = (const f32x4*)(ws + AFRAG_OFF);
        f32x4* dst = (f32x4*)afrag;
        for (int t = threadIdx.x; t < 2048; t += 512) dst[t] = src[t];
    }
    __syncthreads();

    const int p = blockIdx.x*8 + wid;            // < 20736
    int b   = p / NPT;
    int rem = p - b*NPT;
    int i   = rem / MGRID;
    int g   = rem - i*MGRID;

    float a0x = w00[lane*131+0], a0y = w00[lane*131+1], a0z = w00[lane*131+2];
    float a1x = w10[lane*131+0], a1y = w10[lane*131+1], a1z = w10[lane*131+2];

    const float* pr = proposals  + ((size_t)b*NPROP + i)*7;
    const float* gn = grid_noise + (((size_t)b*NPROP + i)*MGRID + g)*3;
    float gx = gn[0]*pr[3], gy = gn[1]*pr[4], gz = gn[2]*pr[5];
    float th = pr[6];
    float ss = sinf(th), cc = cosf(th);
    float nx = cc*gx - ss*gy + pr[0];
    float ny = ss*gx + cc*gy + pr[1];
    float nz = gz + pr[2];
    float pn2 = nx*nx + ny*ny + nz*nz;
    u0l[wid][lane] = a0x*nx + a0y*ny + a0z*nz;
    u1l[wid][lane] = a1x*nx + a1y*ny + a1z*nz;

    // ---- dual-radius ball query: one scan, per-radius guarded processing
    int* idx0 = idx0s[wid];
    int* idx1 = idx1s[wid];
    int cnt0 = 0, cnt1 = 0;
    const f32x4* kx4 = (const f32x4*)(ws + KX4_OFF) + (size_t)b*KPT;
    ull ltm = (1ull << lane) - 1ull;

#define BQ_PROC(D2, RSQ, KK, CNT, IDX, NSV)                                   \
    {                                                                         \
        ull m = __ballot((D2) < RSQ);                                         \
        if (m) {                                                              \
            int pre = __popcll(m & ltm);                                      \
            if (((m >> lane) & 1ull) && CNT + pre < NSV) IDX[CNT + pre] = (KK);\
            CNT += __popcll(m);                                               \
        }                                                                     \
    }

    for (int ck = 0; ck < KPT/64; ck += 2) {
        f32x4 ka  = kx4[ck*64 + lane];
        f32x4 kc2 = kx4[ck*64 + 64 + lane];
        float dta = fmaf(nz, ka.z, fmaf(ny, ka.y, nx*ka.x));
        float d2a = fmaf(-2.f, dta, pn2 + ka.w);
        float dtb = fmaf(nz, kc2.z, fmaf(ny, kc2.y, nx*kc2.x));
        float d2b = fmaf(-2.f, dtb, pn2 + kc2.w);
        int kka = ck*64 + lane, kkb = kka + 64;
        if (cnt0 < NS0) {                        // wave-uniform guard
            BQ_PROC(d2a, R0SQ, kka, cnt0, idx0, NS0)
            BQ_PROC(d2b, R0SQ, kkb, cnt0, idx0, NS0)
        }
        if (cnt1 < NS1) {                        // wave-uniform guard
            BQ_PROC(d2a, R1SQ, kka, cnt1, idx1, NS1)
            BQ_PROC(d2b, R1SQ, kkb, cnt1, idx1, NS1)
        }
        if (cnt0 >= NS0 && cnt1 >= NS1) break;   // wave-uniform
    }
#undef BQ_PROC

    if (lane == 0) {
        if (cnt0 == 0) idx0[0] = 0;              // empty-ball fallback
        if (cnt1 == 0) idx1[0] = 0;
    }
    asm volatile("s_waitcnt lgkmcnt(0)" ::: "memory");
    __builtin_amdgcn_wave_barrier();
    int na0 = cnt0 ? min(cnt0, NS0) : 1;
    int na1 = cnt1 ? min(cnt1, NS1) : 1;
    int f0 = idx0[0], f1 = idx1[0];
    if (lane >= na0 && lane < NS0) idx0[lane] = f0;   // pad like reference
    if (lane >= na1 && lane < NS1) idx1[lane] = f1;
    asm volatile("s_waitcnt lgkmcnt(0)" ::: "memory");
    __builtin_amdgcn_wave_barrier();

    // ---- gather+convert H-fragments for BOTH scales, then MFMA ----
    const float*  Qb0 = ws + Q0_OFF + (size_t)b*(KPT*64);
    const float*  Qb1 = ws + Q0_OFF + (size_t)(2*KPT*64) + (size_t)b*(KPT*64);
    const bf16x8* Whi = (const bf16x8*)afrag;         // LDS
    const bf16x8* Wlo = Whi + 16*64;

    bf16x8 H0hi[1][2], H0lo[1][2], H1hi[2][2], H1lo[2][2];
    build_hfrag<1>(Qb0, idx0, u0l[wid], H0hi, H0lo, lane);
    build_hfrag<2>(Qb1, idx1, u1l[wid], H1hi, H1lo, lane);

    float mx0 = eval_T<1>(Whi, Wlo, b01, H0hi, H0lo, 0, lane);
    float mx1 = eval_T<2>(Whi, Wlo, b11, H1hi, H1lo, 4, lane);

    // coalesced pooled store: poolT[p][c]
    ws[POOL_OFF + (size_t)p*CFEAT + lane]      = mx0;
    ws[POOL_OFF + (size_t)p*CFEAT + 64 + lane] = mx1;
}

// ---------------------------------------------------------------------------
// K_ptr: pool2[r][c*216+g] = poolT[(r*216+g)][c]  (per-row transpose, 21 MB)
// ---------------------------------------------------------------------------
template <int W>
__device__ __forceinline__ void ptr_tile(const float* __restrict__ in,
                                         float* __restrict__ out,
                                         float* __restrict__ t, int g0)
{
    for (int idx = threadIdx.x; idx < 128*W; idx += 256) {
        int gg = idx >> 7, c = idx & 127;
        t[c*(W+1) + gg] = in[(size_t)(g0+gg)*128 + c];   // coalesced along c
    }
    __syncthreads();
    for (int idx = threadIdx.x; idx < 128*W; idx += 256) {
        int c = idx / W, gg = idx - c*W;
        out[c*216 + g0 + gg] = t[c*(W+1) + gg];          // coalesced along g
    }
}

__global__ __launch_bounds__(256) void k_ptr(float* __restrict__ ws)
{
    __shared__ float t[128*33];
    int bid = blockIdx.x;
    int row = bid / 7, tt = bid - row*7;
    const float* in = ws + POOL_OFF + (size_t)row*MGRID*CFEAT;
    float* out = ws + PT_OFF + (size_t)row*KRED;
    if (tt < 6) ptr_tile<32>(in, out, t, tt*32);
    else        ptr_tile<24>(in, out, t, 192);
}

// ---------------------------------------------------------------------------
// K4: part[ks][96][256] = A[96][ksK] * B[256][ksK]^T  (no atomics)
// grid = 108 ksplits x 4 o-tiles of 64; K per split = 256 (4 chunks of 64)
// ---------------------------------------------------------------------------
__global__ __launch_bounds__(256) void k_red0(
    const float* __restrict__ A, const float* __restrict__ w0,
    float* __restrict__ part)
{
    __shared__ __align__(16) float Al[96*68];
    __shared__ __align__(16) float Bl[64*68];
    int bid = blockIdx.x;
    int ot  = bid & 3;
    int ks  = bid >> 2;                      // 0..107
    int tid = threadIdx.x;
    int tx  = tid & 15, ty = tid >> 4;
    float acc[6][4] = {};

    for (int chunk = 0; chunk < 4; ++chunk) {
        int kk0 = ks*256 + chunk*64;
#pragma unroll
        for (int j = 0; j < 6; ++j) {        // stage A 96x64
            int f4i = tid + j*256;
            int rr = f4i >> 4, c4 = f4i & 15;
            float4 v = *(const float4*)(A + (size_t)rr*KRED + kk0 + c4*4);
            *(float4*)(Al + rr*68 + c4*4) = v;
        }
#pragma unroll
        for (int j = 0; j < 4; ++j) {        // stage B 64x64
            int f4i = tid + j*256;
            int rr = f4i >> 4, c4 = f4i & 15;
            float4 v = *(const float4*)(w0 + (size_t)(ot*64+rr)*KRED + kk0 + c4*4);
            *(float4*)(Bl + rr*68 + c4*4) = v;
        }
        __syncthreads();
#pragma unroll
        for (int k4 = 0; k4 < 16; ++k4) {
            float4 av[6], bv[4];
#pragma unroll
            for (int q = 0; q < 6; ++q) av[q] = *(const float4*)(Al + (ty*6+q)*68 + k4*4);
#pragma unroll
            for (int u = 0; u < 4; ++u) bv[u] = *(const float4*)(Bl + (u*16+tx)*68 + k4*4);
#pragma unroll
            for (int q = 0; q < 6; ++q)
#pragma unroll
                for (int u = 0; u < 4; ++u) {
                    acc[q][u] = fmaf(av[q].x, bv[u].x, acc[q][u]);
                    acc[q][u] = fmaf(av[q].y, bv[u].y, acc[q][u]);
                    acc[q][u] = fmaf(av[q].z, bv[u].z, acc[q][u]);
                    acc[q][u] = fmaf(av[q].w, bv[u].w, acc[q][u]);
                }
        }
        __syncthreads();
    }
    float* pp = part + (size_t)ks*(96*256);
#pragma unroll
    for (int q = 0; q < 6; ++q)
#pragma unroll
        for (int u = 0; u < 4; ++u)
            pp[(size_t)(ty*6+q)*256 + ot*64 + u*16 + tx] = acc[q][u];
}

// ---------------------------------------------------------------------------
// K5: out = relu(relu(sum_ks part + b0) @ W1^T + b1)
// ---------------------------------------------------------------------------
__global__ __launch_bounds__(256) void k_fin(
    const float* __restrict__ part, const float* __restrict__ rb0,
    const float* __restrict__ w1, const float* __restrict__ rb1,
    float* __restrict__ out)
{
    __shared__ __align__(16) float hbuf[256];
    int r = blockIdx.x, o = threadIdx.x;
    const float* pp = part + (size_t)r*256 + o;
    float s0 = 0.f, s1 = 0.f, s2 = 0.f, s3 = 0.f;
#pragma unroll 4
    for (int ks = 0; ks < NKSPLIT; ks += 4) {
        s0 += pp[(size_t)(ks+0)*(96*256)];
        s1 += pp[(size_t)(ks+1)*(96*256)];
        s2 += pp[(size_t)(ks+2)*(96*256)];
        s3 += pp[(size_t)(ks+3)*(96*256)];
    }
    float h = fmaxf(((s0 + s1) + (s2 + s3)) + rb0[o], 0.f);
    hbuf[o] = h;
    __syncthreads();
    float a0 = rb1[o], a1 = 0.f, a2 = 0.f, a3 = 0.f;
    const float4* wrow = (const float4*)(w1 + (size_t)o*256);
    const float4* hv   = (const float4*)hbuf;
#pragma unroll 8
    for (int j = 0; j < 64; ++j) {
        float4 w = wrow[j], x = hv[j];
        a0 = fmaf(w.x, x.x, a0);
        a1 = fmaf(w.y, x.y, a1);
        a2 = fmaf(w.z, x.z, a2);
        a3 = fmaf(w.w, x.w, a3);
    }
    out[(size_t)r*256 + o] = fmaxf((a0 + a1) + (a2 + a3), 0.f);
}

// ---------------------------------------------------------------------------
extern "C" void kernel_launch(void* const* d_in, const int* in_sizes, int n_in,
                              void* d_out, int out_size, void* d_ws, size_t ws_size,
                              hipStream_t stream)
{
    (void)in_sizes; (void)n_in; (void)out_size; (void)ws_size;
    const float* proposals = (const float*)d_in[0];
    const float* kxyz      = (const float*)d_in[1];
    const float* feats     = (const float*)d_in[2];
    const float* gnoise    = (const float*)d_in[3];
    const float* w0_0 = (const float*)d_in[4];
    const float* b0_0 = (const float*)d_in[5];
    const float* w0_1 = (const float*)d_in[6];
    const float* b0_1 = (const float*)d_in[7];
    const float* w1_0 = (const float*)d_in[8];
    const float* b1_0 = (const float*)d_in[9];
    const float* w1_1 = (const float*)d_in[10];
    const float* b1_1 = (const float*)d_in[11];
    const float* rw0  = (const float*)d_in[12];
    const float* rb0  = (const float*)d_in[13];
    const float* rw1  = (const float*)d_in[14];
    const float* rb1  = (const float*)d_in[15];
    float* ws  = (float*)d_ws;
    float* out = (float*)d_out;

    k_pre  <<<  80,  64, 0, stream>>>(kxyz, w0_1, w1_1, ws);
    k_qproj<<<2048, 256, 0, stream>>>(kxyz, feats, w0_0, b0_0, w1_0, b1_0, ws);
    k_main <<<2592, 512, 0, stream>>>(proposals, gnoise,
                                      w0_0, b0_1, w1_0, b1_1, ws);
    k_ptr  <<< 672, 256, 0, stream>>>(ws);
    k_red0 <<< 432, 256, 0, stream>>>(ws + PT_OFF, rw0, ws + PART_OFF);
    k_fin  <<<  96, 256, 0, stream>>>(ws + PART_OFF, rb0, rw1, rb1, out);
}

// Round 11
// 229.557 us; speedup vs baseline: 1.1965x; 1.0068x over previous
//
#include <hip/hip_runtime.h>
#include <hip/hip_bf16.h>
#include <cstdint>

#define NPROP  48
#define MGRID  216
#define NPT    (NPROP*MGRID)      // 10368 points per batch
#define KPT    2048
#define CFEAT  128
#define R0SQ   0.64f              // 0.8^2
#define R1SQ   2.56f              // 1.6^2
#define NS0    16
#define NS1    32
#define KRED   (CFEAT*MGRID)      // 27648
#define NPOINTS (2*NPT)           // 20736
#define NKSPLIT 108               // K per split = 256

typedef float f32x4  __attribute__((ext_vector_type(4)));
typedef short bf16x8 __attribute__((ext_vector_type(8)));
typedef unsigned long long ull;

// workspace layout (floats) — total 8,511,488 fl = 34.0 MB
#define AFRAG_OFF 0                           // W-frags hi+lo: 8192 floats (32 KB)
#define KX4_OFF   8192                        // kxyz4 [2][2048] f32x4 = 16384
#define Q0_OFF    24576                       // Q [2 s][2 b][2048 k][64 o] = 524288
#define POOL_OFF  548864                      // poolT [20736 p][128 c] = 2654208
#define PT_OFF    3203072                     // pool2 [96 r][27648 (c*216+g)] = 2654208
#define PART_OFF  5857280                     // part [108 ks][96 r][256 o] = 2654208

__device__ __forceinline__ unsigned short bf_rne(float x) {
    unsigned u = __float_as_uint(x);
    return (unsigned short)((u + 0x7fffu + ((u >> 16) & 1u)) >> 16);
}
__device__ __forceinline__ float bf_f32(unsigned short h) {
    return __uint_as_float(((unsigned)h) << 16);
}
__device__ __forceinline__ unsigned short bf_cvt(float x) {   // HW RTNE cvt
    union { __hip_bfloat16 h; unsigned short u; } c;
    c.h = __float2bfloat16(x);
    return c.u;
}

// ---------------------------------------------------------------------------
// K_prep (merged): blocks 0-3: layer-2 weight fragments (hi/lo bf16 split).
//   Fragment layout (symmetric A/B of 16x16x32): lane l holds
//   X[idx=l&15][k=(l>>4)*8+j], j=0..7. Used as the B operand (idx=channel).
// blocks 4-19: pack kxyz4 = (x,y,z,kn2).
// blocks 20-2067: Q[s][b][k][o] = b0_s[o] + W_s[o][0:3].kxyz + W_s[o][3:].feats
// ---------------------------------------------------------------------------
__global__ __launch_bounds__(256) void k_prep(
    const float* __restrict__ kxyz, const float* __restrict__ feats,
    const float* __restrict__ w00, const float* __restrict__ b00,
    const float* __restrict__ w10, const float* __restrict__ b10,
    const float* __restrict__ w01, const float* __restrict__ w11,
    float* __restrict__ ws)
{
    __shared__ float shmem[64*131];
    int bid = blockIdx.x;
    if (bid < 4) {
        // ---- layer-2 W fragments: 16 frag-units, 4 per block
        int sub = threadIdx.x >> 6, l = threadIdx.x & 63;
        int fid = bid*4 + sub;                   // 0..15
        int kc = fid & 1, ot = (fid >> 1) & 3, s = fid >> 3;
        const float* W = s ? w11 : w01;
        int row = ot*16 + (l & 15);
        int k0  = kc*32 + (l >> 4)*8;
        union { unsigned short u16[8]; bf16x8 v; } hh, hl;
#pragma unroll
        for (int j = 0; j < 8; ++j) {
            float x  = W[row*64 + k0 + j];
            unsigned short hi = bf_rne(x);
            hh.u16[j] = hi;
            hl.u16[j] = bf_rne(x - bf_f32(hi));
        }
        bf16x8* Whi = (bf16x8*)(ws + AFRAG_OFF);
        bf16x8* Wlo = Whi + 16*64;
        int fi = (s*4 + ot)*2 + kc;
        Whi[fi*64 + l] = hh.v;
        Wlo[fi*64 + l] = hl.v;
    } else if (bid < 20) {
        // ---- kxyz4 pack
        int idx = (bid - 4)*256 + threadIdx.x;   // < 4096 = b*KPT + k
        const float* kp = kxyz + (size_t)idx*3;
        float kx = kp[0], ky = kp[1], kz = kp[2];
        float kn2 = fmaf(kz, kz, fmaf(ky, ky, kx*kx));
        f32x4 v = {kx, ky, kz, kn2};
        ((f32x4*)(ws + KX4_OFF))[idx] = v;
    } else {
        // ---- Q projection
        int qb   = bid - 20;                     // 0..2047
        int kgrp = qb & 511;
        int s    = (qb >> 9) & 1;
        int b    = qb >> 10;
        const float* W    = s ? w10 : w00;
        const float* bias = s ? b10 : b00;
        for (int i = threadIdx.x; i < 64*131; i += 256) shmem[i] = W[i];
        __syncthreads();
        int k = kgrp*4 + (threadIdx.x >> 6);
        int o = threadIdx.x & 63;
        float acc = bias[o];
        const float* kp = kxyz + ((size_t)b*KPT + k)*3;
        acc = fmaf(shmem[o*131+0], kp[0], acc);
        acc = fmaf(shmem[o*131+1], kp[1], acc);
        acc = fmaf(shmem[o*131+2], kp[2], acc);
        const float* f = feats + (size_t)b*CFEAT*KPT + k;
#pragma unroll 8
        for (int c = 0; c < CFEAT; ++c)
            acc = fmaf(shmem[o*131+3+c], f[(size_t)c*KPT], acc);
        ws[Q0_OFF + (size_t)s*(2*KPT*64) + ((size_t)b*KPT + k)*64 + o] = acc;
    }
}

// ---------------------------------------------------------------------------
// K3 main: one WAVE per point. Swapped-operand MFMA: D = H(samples) x W2^T,
// sample-max pool = reg-max + 2 shfl_xor.
// ---------------------------------------------------------------------------
template <int NST>
__device__ __forceinline__ void build_hfrag(
    const float* __restrict__ Qb, const int* __restrict__ idxl,
    const float* __restrict__ u_lds,
    bf16x8 (&Hhi)[NST][2], bf16x8 (&Hlo)[NST][2], int lane)
{
    const int g = lane >> 4;
#pragma unroll
    for (int st = 0; st < NST; ++st) {
        int sp = idxl[st*16 + (lane & 15)];
        const float* qr = Qb + ((size_t)sp << 6) + g*8;
#pragma unroll
        for (int kc = 0; kc < 2; ++kc) {
            f32x4 q0 = *(const f32x4*)(qr + kc*32);
            f32x4 q1 = *(const f32x4*)(qr + kc*32 + 4);
            f32x4 u0 = *(const f32x4*)(u_lds + kc*32 + g*8);
            f32x4 u1 = *(const f32x4*)(u_lds + kc*32 + g*8 + 4);
            union { unsigned short u16[8]; bf16x8 v; } hh, hl;
#pragma unroll
            for (int j = 0; j < 4; ++j) {
                float x = fmaxf(q0[j] - u0[j], 0.f);
                unsigned short hi = bf_cvt(x);           // HW RTNE
                hh.u16[j] = hi;
                hl.u16[j] = bf_cvt(x - bf_f32(hi));
                float y = fmaxf(q1[j] - u1[j], 0.f);
                unsigned short hi2 = bf_cvt(y);
                hh.u16[j+4] = hi2;
                hl.u16[j+4] = bf_cvt(y - bf_f32(hi2));
            }
            Hhi[st][kc] = hh.v;
            Hlo[st][kc] = hl.v;
        }
    }
}

template <int NST>
__device__ __forceinline__ float eval_T(
    const bf16x8* Whi, const bf16x8* Wlo,      // LDS W-fragments
    const float* __restrict__ bs,
    const bf16x8 (&Hhi)[NST][2], const bf16x8 (&Hlo)[NST][2],
    int sbase, int lane)
{
    float r0, r1, r2, r3;
#define EVAL_OT(OT, ROUT)                                                     \
    {                                                                         \
        int fi = (sbase + (OT))*2;                                            \
        bf16x8 wh0 = Whi[(fi+0)*64 + lane];                                   \
        bf16x8 wh1 = Whi[(fi+1)*64 + lane];                                   \
        bf16x8 wl0 = Wlo[(fi+0)*64 + lane];                                   \
        bf16x8 wl1 = Wlo[(fi+1)*64 + lane];                                   \
        float bc = bs[(OT)*16 + (lane & 15)];                                 \
        f32x4 rmax = {0.f, 0.f, 0.f, 0.f};                                    \
        _Pragma("unroll")                                                     \
        for (int st = 0; st < NST; ++st) {                                    \
            f32x4 accA = {0.f, 0.f, 0.f, 0.f};                                \
            f32x4 accB = {0.f, 0.f, 0.f, 0.f};                                \
            accA = __builtin_amdgcn_mfma_f32_16x16x32_bf16(Hlo[st][0], wh0, accA, 0,0,0); \
            accB = __builtin_amdgcn_mfma_f32_16x16x32_bf16(Hlo[st][1], wh1, accB, 0,0,0); \
            accA = __builtin_amdgcn_mfma_f32_16x16x32_bf16(Hhi[st][0], wl0, accA, 0,0,0); \
            accB = __builtin_amdgcn_mfma_f32_16x16x32_bf16(Hhi[st][1], wl1, accB, 0,0,0); \
            accA = __builtin_amdgcn_mfma_f32_16x16x32_bf16(Hhi[st][0], wh0, accA, 0,0,0); \
            accB = __builtin_amdgcn_mfma_f32_16x16x32_bf16(Hhi[st][1], wh1, accB, 0,0,0); \
            _Pragma("unroll")                                                 \
            for (int r = 0; r < 4; ++r)                                       \
                rmax[r] = fmaxf(rmax[r], fmaxf((accA[r] + accB[r]) + bc, 0.f)); \
        }                                                                     \
        float mm = fmaxf(fmaxf(rmax[0], rmax[1]), fmaxf(rmax[2], rmax[3]));   \
        mm = fmaxf(mm, __shfl_xor(mm, 16));                                   \
        mm = fmaxf(mm, __shfl_xor(mm, 32));                                   \
        ROUT = mm;                                                            \
    }
    EVAL_OT(0, r0) EVAL_OT(1, r1) EVAL_OT(2, r2) EVAL_OT(3, r3)
#undef EVAL_OT
    float v01 = (lane & 16) ? r1 : r0;
    float v23 = (lane & 16) ? r3 : r2;
    return (lane & 32) ? v23 : v01;
}

__global__ __launch_bounds__(512, 4) void k_main(   // cap 128 VGPR: no spill
    const float* __restrict__ proposals, const float* __restrict__ grid_noise,
    const float* __restrict__ w00, const float* __restrict__ b01,
    const float* __restrict__ w10, const float* __restrict__ b11,
    float* __restrict__ ws)
{
    __shared__ __align__(16) float afrag[8192];      // 32 KB: Whi | Wlo
    __shared__ int idx0s[8][NS0];
    __shared__ int idx1s[8][NS1];
    __shared__ __align__(16) float u0l[8][64], u1l[8][64];
    const int wid  = threadIdx.x >> 6;
    const int lane = threadIdx.x & 63;

    // ---- cooperative stage of all W-fragments into LDS (once per block)
    {
        const f32x4* src = (const f32x4*)(ws + AFRAG_OFF);
        f32x4* dst = (f32x4*)afrag;
        for (int t = threadIdx.x; t < 2048; t += 512) dst[t] = src[t];
    }
    __syncthreads();

    const int p = blockIdx.x*8 + wid;            // < 20736
    int b   = p / NPT;
    int rem = p - b*NPT;
    int i   = rem / MGRID;
    int g   = rem - i*MGRID;

    float a0x = w00[lane*131+0], a0y = w00[lane*131+1], a0z = w00[lane*131+2];
    float a1x = w10[lane*131+0], a1y = w10[lane*131+1], a1z = w10[lane*131+2];

    const float* pr = proposals  + ((size_t)b*NPROP + i)*7;
    const float* gn = grid_noise + (((size_t)b*NPROP + i)*MGRID + g)*3;
    float gx = gn[0]*pr[3], gy = gn[1]*pr[4], gz = gn[2]*pr[5];
    float th = pr[6];
    float ss = sinf(th), cc = cosf(th);
    float nx = cc*gx - ss*gy + pr[0];
    float ny = ss*gx + cc*gy + pr[1];
    float nz = gz + pr[2];
    float pn2 = nx*nx + ny*ny + nz*nz;
    u0l[wid][lane] = a0x*nx + a0y*ny + a0z*nz;
    u1l[wid][lane] = a1x*nx + a1y*ny + a1z*nz;

    // ---- dual-radius ball query: one scan, per-radius guarded processing
    int* idx0 = idx0s[wid];
    int* idx1 = idx1s[wid];
    int cnt0 = 0, cnt1 = 0;
    const f32x4* kx4 = (const f32x4*)(ws + KX4_OFF) + (size_t)b*KPT;
    ull ltm = (1ull << lane) - 1ull;

#define BQ_PROC(D2, RSQ, KK, CNT, IDX, NSV)                                   \
    {                                                                         \
        ull m = __ballot((D2) < RSQ);                                         \
        if (m) {                                                              \
            int pre = __popcll(m & ltm);                                      \
            if (((m >> lane) & 1ull) && CNT + pre < NSV) IDX[CNT + pre] = (KK);\
            CNT += __popcll(m);                                               \
        }                                                                     \
    }

    for (int ck = 0; ck < KPT/64; ck += 2) {
        f32x4 ka  = kx4[ck*64 + lane];
        f32x4 kc2 = kx4[ck*64 + 64 + lane];
        float dta = fmaf(nz, ka.z, fmaf(ny, ka.y, nx*ka.x));
        float d2a = fmaf(-2.f, dta, pn2 + ka.w);
        float dtb = fmaf(nz, kc2.z, fmaf(ny, kc2.y, nx*kc2.x));
        float d2b = fmaf(-2.f, dtb, pn2 + kc2.w);
        int kka = ck*64 + lane, kkb = kka + 64;
        if (cnt0 < NS0) {                        // wave-uniform guard
            BQ_PROC(d2a, R0SQ, kka, cnt0, idx0, NS0)
            BQ_PROC(d2b, R0SQ, kkb, cnt0, idx0, NS0)
        }
        if (cnt1 < NS1) {                        // wave-uniform guard
            BQ_PROC(d2a, R1SQ, kka, cnt1, idx1, NS1)
            BQ_PROC(d2b, R1SQ, kkb, cnt1, idx1, NS1)
        }
        if (cnt0 >= NS0 && cnt1 >= NS1) break;   // wave-uniform
    }
#undef BQ_PROC

    if (lane == 0) {
        if (cnt0 == 0) idx0[0] = 0;              // empty-ball fallback
        if (cnt1 == 0) idx1[0] = 0;
    }
    asm volatile("s_waitcnt lgkmcnt(0)" ::: "memory");
    __builtin_amdgcn_wave_barrier();
    int na0 = cnt0 ? min(cnt0, NS0) : 1;
    int na1 = cnt1 ? min(cnt1, NS1) : 1;
    int f0 = idx0[0], f1 = idx1[0];
    if (lane >= na0 && lane < NS0) idx0[lane] = f0;   // pad like reference
    if (lane >= na1 && lane < NS1) idx1[lane] = f1;
    asm volatile("s_waitcnt lgkmcnt(0)" ::: "memory");
    __builtin_amdgcn_wave_barrier();

    // ---- gather+convert H-fragments for BOTH scales, then MFMA ----
    const float*  Qb0 = ws + Q0_OFF + (size_t)b*(KPT*64);
    const float*  Qb1 = ws + Q0_OFF + (size_t)(2*KPT*64) + (size_t)b*(KPT*64);
    const bf16x8* Whi = (const bf16x8*)afrag;         // LDS
    const bf16x8* Wlo = Whi + 16*64;

    bf16x8 H0hi[1][2], H0lo[1][2], H1hi[2][2], H1lo[2][2];
    build_hfrag<1>(Qb0, idx0, u0l[wid], H0hi, H0lo, lane);
    build_hfrag<2>(Qb1, idx1, u1l[wid], H1hi, H1lo, lane);

    float mx0 = eval_T<1>(Whi, Wlo, b01, H0hi, H0lo, 0, lane);
    float mx1 = eval_T<2>(Whi, Wlo, b11, H1hi, H1lo, 4, lane);

    // coalesced pooled store: poolT[p][c]
    ws[POOL_OFF + (size_t)p*CFEAT + lane]      = mx0;
    ws[POOL_OFF + (size_t)p*CFEAT + 64 + lane] = mx1;
}

// ---------------------------------------------------------------------------
// K_ptr: pool2[r][c*216+g] = poolT[(r*216+g)][c]  (per-row transpose, 21 MB)
// ---------------------------------------------------------------------------
template <int W>
__device__ __forceinline__ void ptr_tile(const float* __restrict__ in,
                                         float* __restrict__ out,
                                         float* __restrict__ t, int g0)
{
    for (int idx = threadIdx.x; idx < 128*W; idx += 256) {
        int gg = idx >> 7, c = idx & 127;
        t[c*(W+1) + gg] = in[(size_t)(g0+gg)*128 + c];   // coalesced along c
    }
    __syncthreads();
    for (int idx = threadIdx.x; idx < 128*W; idx += 256) {
        int c = idx / W, gg = idx - c*W;
        out[c*216 + g0 + gg] = t[c*(W+1) + gg];          // coalesced along g
    }
}

__global__ __launch_bounds__(256) void k_ptr(float* __restrict__ ws)
{
    __shared__ float t[128*33];
    int bid = blockIdx.x;
    int row = bid / 7, tt = bid - row*7;
    const float* in = ws + POOL_OFF + (size_t)row*MGRID*CFEAT;
    float* out = ws + PT_OFF + (size_t)row*KRED;
    if (tt < 6) ptr_tile<32>(in, out, t, tt*32);
    else        ptr_tile<24>(in, out, t, 192);
}

// ---------------------------------------------------------------------------
// K4: part[ks][96][256] = A[96][ksK] * B[256][ksK]^T  (no atomics)
// grid = 108 ksplits x 4 o-tiles of 64; K per split = 256 (4 chunks of 64)
// ---------------------------------------------------------------------------
__global__ __launch_bounds__(256) void k_red0(
    const float* __restrict__ A, const float* __restrict__ w0,
    float* __restrict__ part)
{
    __shared__ __align__(16) float Al[96*68];
    __shared__ __align__(16) float Bl[64*68];
    int bid = blockIdx.x;
    int ot  = bid & 3;
    int ks  = bid >> 2;                      // 0..107
    int tid = threadIdx.x;
    int tx  = tid & 15, ty = tid >> 4;
    float acc[6][4] = {};

    for (int chunk = 0; chunk < 4; ++chunk) {
        int kk0 = ks*256 + chunk*64;
#pragma unroll
        for (int j = 0; j < 6; ++j) {        // stage A 96x64
            int f4i = tid + j*256;
            int rr = f4i >> 4, c4 = f4i & 15;
            float4 v = *(const float4*)(A + (size_t)rr*KRED + kk0 + c4*4);
            *(float4*)(Al + rr*68 + c4*4) = v;
        }
#pragma unroll
        for (int j = 0; j < 4; ++j) {        // stage B 64x64
            int f4i = tid + j*256;
            int rr = f4i >> 4, c4 = f4i & 15;
            float4 v = *(const float4*)(w0 + (size_t)(ot*64+rr)*KRED + kk0 + c4*4);
            *(float4*)(Bl + rr*68 + c4*4) = v;
        }
        __syncthreads();
#pragma unroll
        for (int k4 = 0; k4 < 16; ++k4) {
            float4 av[6], bv[4];
#pragma unroll
            for (int q = 0; q < 6; ++q) av[q] = *(const float4*)(Al + (ty*6+q)*68 + k4*4);
#pragma unroll
            for (int u = 0; u < 4; ++u) bv[u] = *(const float4*)(Bl + (u*16+tx)*68 + k4*4);
#pragma unroll
            for (int q = 0; q < 6; ++q)
#pragma unroll
                for (int u = 0; u < 4; ++u) {
                    acc[q][u] = fmaf(av[q].x, bv[u].x, acc[q][u]);
                    acc[q][u] = fmaf(av[q].y, bv[u].y, acc[q][u]);
                    acc[q][u] = fmaf(av[q].z, bv[u].z, acc[q][u]);
                    acc[q][u] = fmaf(av[q].w, bv[u].w, acc[q][u]);
                }
        }
        __syncthreads();
    }
    float* pp = part + (size_t)ks*(96*256);
#pragma unroll
    for (int q = 0; q < 6; ++q)
#pragma unroll
        for (int u = 0; u < 4; ++u)
            pp[(size_t)(ty*6+q)*256 + ot*64 + u*16 + tx] = acc[q][u];
}

// ---------------------------------------------------------------------------
// K5: out = relu(relu(sum_ks part + b0) @ W1^T + b1)
// ---------------------------------------------------------------------------
__global__ __launch_bounds__(256) void k_fin(
    const float* __restrict__ part, const float* __restrict__ rb0,
    const float* __restrict__ w1, const float* __restrict__ rb1,
    float* __restrict__ out)
{
    __shared__ __align__(16) float hbuf[256];
    int r = blockIdx.x, o = threadIdx.x;
    const float* pp = part + (size_t)r*256 + o;
    float s0 = 0.f, s1 = 0.f, s2 = 0.f, s3 = 0.f;
#pragma unroll 4
    for (int ks = 0; ks < NKSPLIT; ks += 4) {
        s0 += pp[(size_t)(ks+0)*(96*256)];
        s1 += pp[(size_t)(ks+1)*(96*256)];
        s2 += pp[(size_t)(ks+2)*(96*256)];
        s3 += pp[(size_t)(ks+3)*(96*256)];
    }
    float h = fmaxf(((s0 + s1) + (s2 + s3)) + rb0[o], 0.f);
    hbuf[o] = h;
    __syncthreads();
    float a0 = rb1[o], a1 = 0.f, a2 = 0.f, a3 = 0.f;
    const float4* wrow = (const float4*)(w1 + (size_t)o*256);
    const float4* hv   = (const float4*)hbuf;
#pragma unroll 8
    for (int j = 0; j < 64; ++j) {
        float4 w = wrow[j], x = hv[j];
        a0 = fmaf(w.x, x.x, a0);
        a1 = fmaf(w.y, x.y, a1);
        a2 = fmaf(w.z, x.z, a2);
        a3 = fmaf(w.w, x.w, a3);
    }
    out[(size_t)r*256 + o] = fmaxf((a0 + a1) + (a2 + a3), 0.f);
}

// ---------------------------------------------------------------------------
extern "C" void kernel_launch(void* const* d_in, const int* in_sizes, int n_in,
                              void* d_out, int out_size, void* d_ws, size_t ws_size,
                              hipStream_t stream)
{
    (void)in_sizes; (void)n_in; (void)out_size; (void)ws_size;
    const float* proposals = (const float*)d_in[0];
    const float* kxyz      = (const float*)d_in[1];
    const float* feats     = (const float*)d_in[2];
    const float* gnoise    = (const float*)d_in[3];
    const float* w0_0 = (const float*)d_in[4];
    const float* b0_0 = (const float*)d_in[5];
    const float* w0_1 = (const float*)d_in[6];
    const float* b0_1 = (const float*)d_in[7];
    const float* w1_0 = (const float*)d_in[8];
    const float* b1_0 = (const float*)d_in[9];
    const float* w1_1 = (const float*)d_in[10];
    const float* b1_1 = (const float*)d_in[11];
    const float* rw0  = (const float*)d_in[12];
    const float* rb0  = (const float*)d_in[13];
    const float* rw1  = (const float*)d_in[14];
    const float* rb1  = (const float*)d_in[15];
    float* ws  = (float*)d_ws;
    float* out = (float*)d_out;

    k_prep <<<2068, 256, 0, stream>>>(kxyz, feats, w0_0, b0_0, w1_0, b1_0,
                                      w0_1, w1_1, ws);
    k_main <<<2592, 512, 0, stream>>>(proposals, gnoise,
                                      w0_0, b0_1, w1_0, b1_1, ws);
    k_ptr  <<< 672, 256, 0, stream>>>(ws);
    k_red0 <<< 432, 256, 0, stream>>>(ws + PT_OFF, rw0, ws + PART_OFF);
    k_fin  <<<  96, 256, 0, stream>>>(ws + PART_OFF, rb0, rw1, rb1, out);
}